// Round 8
// baseline (93.927 us; speedup 1.0000x reference)
//
#include <hip/hip_runtime.h>
#include <hip/hip_bf16.h>

// memristor_dense: y[b,j] = sum_i A[i,2j]*2^(e[i,2j]*l[b,i]) - A[i,2j+1]*2^(e[i,2j+1]*l[b,i])
//   A[i,j] = 0.5*|w[i,j]| + max_w/18      (folds G, V_REF, 1/(K_V*k_G), G_MIN)
//   e[i,j] = log2(n_param[i,j]) + 1
//   l[b,i] = log2(2*clip(x[b,i],0,1))     (log2(0)=-inf -> exp2(-inf)=0 handles x==0 mask)
// shapes: x(128,1024), w_pos/w_neg(1024,512), b_pos/b_neg(512), n_param(1025,1024)
//
// R7 -> R8: register-block 2 batch rows per thread. Pipe model of R7 inner
// loop: LDS issue 17.8 cyc/pair (b128+b32) > trans 16 > VALU 8 -> LDS-bound.
// Amortizing the b128 param read over 2 rows: LDS 23.6/2pairs = 11.8, trans
// 16/pair binding = true floor (~6.8us chip). 128-thread blocks (16jj x 8bq,
// rows bq & bq+8), grid (32,8,4) unchanged -> 21KB LDS -> 7 blocks/CU = 14
// waves/CU (R6 showed 1 block/CU fails; this keeps TLP). Setup unchanged:
// atomicMax into poisoned ws (0xAAAAAAAA<0 as int), y zeroed in setup,
// 2 dispatches, no memset.

#define LOG2F(v)  __builtin_amdgcn_logf(v)    // v_log_f32: log2(x)
#define EXP2F(v)  __builtin_amdgcn_exp2f(v)   // v_exp_f32: 2^x

#define NJ 16        // jpairs per block
#define NB 16        // batch rows per block (2 per thread)
#define KI 64        // k-chunk
#define KROW4 65     // sP row stride in float4
#define LROW 68      // sL row stride in floats

__global__ __launch_bounds__(256) void setup_kernel(
    const float* __restrict__ w_pos, const float* __restrict__ w_neg,
    const float* __restrict__ b_pos, const float* __restrict__ b_neg,
    float* __restrict__ y, int* __restrict__ ws) {
  const int t = threadIdx.x, blk = blockIdx.x;
  // zero d_out: 16384 float4 over 256 blocks = 64 per block
  float4* y4 = (float4*)y;
  if (t < 64) y4[blk * 64 + t] = make_float4(0.f, 0.f, 0.f, 0.f);
  // |w| max partial: each array 131072 float4 -> 512 per block -> 2 per thread
  const float4* wp4 = (const float4*)w_pos;
  const float4* wn4 = (const float4*)w_neg;
  float m = 0.0f;
  #pragma unroll
  for (int r = 0; r < 2; ++r) {
    int i = blk * 512 + r * 256 + t;
    float4 a = wp4[i], b = wn4[i];
    m = fmaxf(m, fmaxf(fmaxf(fabsf(a.x), fabsf(a.y)), fmaxf(fabsf(a.z), fabsf(a.w))));
    m = fmaxf(m, fmaxf(fmaxf(fabsf(b.x), fabsf(b.y)), fmaxf(fabsf(b.z), fabsf(b.w))));
  }
  if (blk == 0) {
    m = fmaxf(m, fmaxf(fabsf(b_pos[t]), fabsf(b_pos[t + 256])));
    m = fmaxf(m, fmaxf(fabsf(b_neg[t]), fabsf(b_neg[t + 256])));
  }
  #pragma unroll
  for (int off = 32; off > 0; off >>= 1)
    m = fmaxf(m, __shfl_down(m, off, 64));
  __shared__ float sm[4];
  int lane = t & 63, wv = t >> 6;
  if (lane == 0) sm[wv] = m;
  __syncthreads();
  if (t == 0) {
    m = fmaxf(fmaxf(sm[0], sm[1]), fmaxf(sm[2], sm[3]));
    // positive-float bits compare correctly as int; poisoned 0xAAAAAAAA is
    // negative as int, so ws needs no initialization.
    atomicMax(ws, __float_as_int(m));
  }
}

__global__ __launch_bounds__(128) void memristor_kernel(
    const float* __restrict__ x, const float* __restrict__ w_pos,
    const float* __restrict__ w_neg, const float* __restrict__ b_pos,
    const float* __restrict__ b_neg, const float* __restrict__ n_param,
    const float* __restrict__ ws, float* __restrict__ y) {
  __shared__ float4 sP[NJ * KROW4];
  __shared__ float  sL[NB * LROW];

  const float mw = __int_as_float(((const int*)ws)[0]);
  const float c0 = mw * (0.05f / 0.9f);   // G_MIN*V_REF/(K_V*k_G) = max_w/18

  const int j0 = blockIdx.x * NJ;   // 32 j-tiles
  const int b0 = blockIdx.y * NB;   // 8 b-tiles
  const int zt = blockIdx.z;        // 4-way i-split: rows [zt*256, zt*256+256)
  const int t  = threadIdx.x;       // 128 threads
  const int jj = t & 15;
  const int bq = t >> 4;            // [0,8): handles rows bq and bq+8
  float acc0 = 0.0f, acc1 = 0.0f;

  const float2* np2 = (const float2*)n_param;

  for (int c = 0; c < 4; ++c) {
    const int i0 = zt * 256 + c * KI;
    // stage x -> l = log2(2*clip(x)) : 16 rows x 64, 8 per thread
    #pragma unroll
    for (int r = 0; r < (NB * KI) / 128; ++r) {
      int idx = r * 128 + t;
      int k  = idx & (KI - 1);
      int bl = idx >> 6;
      float v = x[(b0 + bl) * 1024 + i0 + k];
      v = fminf(fmaxf(v, 0.0f), 1.0f);
      sL[bl * LROW + k] = LOG2F(2.0f * v);
    }
    // stage params as float4 {A0, E0, A1, E1} : 16 jpairs x 64 k, 8 per thread
    #pragma unroll
    for (int r = 0; r < (NJ * KI) / 128; ++r) {
      int idx = r * 128 + t;
      int jl = idx & (NJ - 1);
      int il = idx >> 4;
      int gi = i0 + il;
      float wp = w_pos[gi * 512 + j0 + jl];
      float wn = w_neg[gi * 512 + j0 + jl];
      float2 np = np2[gi * 512 + j0 + jl];   // (n[i,2j], n[i,2j+1])
      sP[jl * KROW4 + il] = make_float4(
          fmaf(0.5f, fabsf(wp), c0), LOG2F(np.x) + 1.0f,
          fmaf(0.5f, fabsf(wn), c0), LOG2F(np.y) + 1.0f);
    }
    __syncthreads();
    const float4* pP  = &sP[jj * KROW4];
    const float*  pL0 = &sL[bq * LROW];
    const float*  pL1 = &sL[(bq + 8) * LROW];
    #pragma unroll 8
    for (int k = 0; k < KI; ++k) {
      float4 p = pP[k];
      float l0 = pL0[k];
      float l1 = pL1[k];
      acc0 = fmaf(p.x, EXP2F(p.y * l0), acc0);
      acc0 = fmaf(-p.z, EXP2F(p.w * l0), acc0);
      acc1 = fmaf(p.x, EXP2F(p.y * l1), acc1);
      acc1 = fmaf(-p.z, EXP2F(p.w * l1), acc1);
    }
    __syncthreads();
  }

  if (zt == 3) {
    // bias row i = 1024: inp = 1 -> vr = 2 -> 2^e
    int jg = j0 + jj;
    float2 np = np2[1024 * 512 + jg];
    float a0 = fmaf(0.5f, fabsf(b_pos[jg]), c0);
    float a1 = fmaf(0.5f, fabsf(b_neg[jg]), c0);
    float bias = a0 * EXP2F(LOG2F(np.x) + 1.0f) - a1 * EXP2F(LOG2F(np.y) + 1.0f);
    acc0 += bias;
    acc1 += bias;
  }

  atomicAdd(&y[(b0 + bq) * 512 + (j0 + jj)], acc0);
  atomicAdd(&y[(b0 + bq + 8) * 512 + (j0 + jj)], acc1);
}

extern "C" void kernel_launch(void* const* d_in, const int* in_sizes, int n_in,
                              void* d_out, int out_size, void* d_ws, size_t ws_size,
                              hipStream_t stream) {
  const float* x       = (const float*)d_in[0];
  const float* w_pos   = (const float*)d_in[1];
  const float* w_neg   = (const float*)d_in[2];
  const float* b_pos   = (const float*)d_in[3];
  const float* b_neg   = (const float*)d_in[4];
  const float* n_param = (const float*)d_in[5];
  float* y   = (float*)d_out;

  setup_kernel<<<dim3(256), dim3(256), 0, stream>>>(
      w_pos, w_neg, b_pos, b_neg, y, (int*)d_ws);

  memristor_kernel<<<dim3(32, 8, 4), dim3(128), 0, stream>>>(
      x, w_pos, w_neg, b_pos, b_neg, n_param, (const float*)d_ws, y);
}

// Round 9
// 91.468 us; speedup vs baseline: 1.0269x; 1.0269x over previous
//
#include <hip/hip_runtime.h>
#include <hip/hip_bf16.h>

// memristor_dense: y[b,j] = sum_i A[i,2j]*2^(e[i,2j]*l[b,i]) - A[i,2j+1]*2^(e[i,2j+1]*l[b,i])
//   A[i,j] = 0.5*|w[i,j]| + max_w/18      (folds G, V_REF, 1/(K_V*k_G), G_MIN)
//   e[i,j] = log2(n_param[i,j]) + 1
//   l[b,i] = log2(2*clip(x[b,i],0,1))     (log2(0)=-inf -> exp2(-inf)=0 handles x==0 mask)
// shapes: x(128,1024), w_pos/w_neg(1024,512), b_pos/b_neg(512), n_param(1025,1024)
//
// R8 -> R9: occupancy push. Back-solved from R6 (main=40.7us @ 4 waves/CU) and
// R3/R7/R8 (main=26.8us @ 16 waves/CU, invariant to per-thread blocking/LDS
// layout): kernel is TLP-bound packing the trans pipe (0.373 -> 0.245 cyc/E
// going 4->16 waves/CU). Occupancy is GRID-limited (1024 blocks = 4 blocks/CU;
// LDS 21KB permits 7). z-split 4 -> 8: grid 2048, ~7 blocks/CU = 28 waves/CU.
// Setup unchanged: atomicMax into poisoned ws (0xAAAAAAAA<0 as int), y zeroed
// in setup, 2 dispatches, no memset.

#define LOG2F(v)  __builtin_amdgcn_logf(v)    // v_log_f32: log2(x)
#define EXP2F(v)  __builtin_amdgcn_exp2f(v)   // v_exp_f32: 2^x

#define NJ 16        // jpairs per block
#define NB 16        // batch rows per block
#define KI 64        // k-chunk
#define KROW4 65     // sP row stride in float4 (bank offset 4 -> 2-way alias = free)
#define LROW 68      // sL row stride in floats

__global__ __launch_bounds__(256) void setup_kernel(
    const float* __restrict__ w_pos, const float* __restrict__ w_neg,
    const float* __restrict__ b_pos, const float* __restrict__ b_neg,
    float* __restrict__ y, int* __restrict__ ws) {
  const int t = threadIdx.x, blk = blockIdx.x;
  // zero d_out: 16384 float4 over 256 blocks = 64 per block
  float4* y4 = (float4*)y;
  if (t < 64) y4[blk * 64 + t] = make_float4(0.f, 0.f, 0.f, 0.f);
  // |w| max partial: each array 131072 float4 -> 512 per block -> 2 per thread
  const float4* wp4 = (const float4*)w_pos;
  const float4* wn4 = (const float4*)w_neg;
  float m = 0.0f;
  #pragma unroll
  for (int r = 0; r < 2; ++r) {
    int i = blk * 512 + r * 256 + t;
    float4 a = wp4[i], b = wn4[i];
    m = fmaxf(m, fmaxf(fmaxf(fabsf(a.x), fabsf(a.y)), fmaxf(fabsf(a.z), fabsf(a.w))));
    m = fmaxf(m, fmaxf(fmaxf(fabsf(b.x), fabsf(b.y)), fmaxf(fabsf(b.z), fabsf(b.w))));
  }
  if (blk == 0) {
    m = fmaxf(m, fmaxf(fabsf(b_pos[t]), fabsf(b_pos[t + 256])));
    m = fmaxf(m, fmaxf(fabsf(b_neg[t]), fabsf(b_neg[t + 256])));
  }
  #pragma unroll
  for (int off = 32; off > 0; off >>= 1)
    m = fmaxf(m, __shfl_down(m, off, 64));
  __shared__ float sm[4];
  int lane = t & 63, wv = t >> 6;
  if (lane == 0) sm[wv] = m;
  __syncthreads();
  if (t == 0) {
    m = fmaxf(fmaxf(sm[0], sm[1]), fmaxf(sm[2], sm[3]));
    // positive-float bits compare correctly as int; poisoned 0xAAAAAAAA is
    // negative as int, so ws needs no initialization.
    atomicMax(ws, __float_as_int(m));
  }
}

__global__ __launch_bounds__(256) void memristor_kernel(
    const float* __restrict__ x, const float* __restrict__ w_pos,
    const float* __restrict__ w_neg, const float* __restrict__ b_pos,
    const float* __restrict__ b_neg, const float* __restrict__ n_param,
    const float* __restrict__ ws, float* __restrict__ y) {
  __shared__ float4 sP[NJ * KROW4];
  __shared__ float  sL[NB * LROW];

  const float mw = __int_as_float(((const int*)ws)[0]);
  const float c0 = mw * (0.05f / 0.9f);   // G_MIN*V_REF/(K_V*k_G) = max_w/18

  const int j0 = blockIdx.x * NJ;   // 32 j-tiles
  const int b0 = blockIdx.y * NB;   // 8 b-tiles
  const int zt = blockIdx.z;        // 8-way i-split: rows [zt*128, zt*128+128)
  const int t  = threadIdx.x;
  const int jj = t & 15;
  const int bb = t >> 4;
  float accP = 0.0f, accN = 0.0f;

  const float2* np2 = (const float2*)n_param;

  for (int c = 0; c < 2; ++c) {
    const int i0 = zt * 128 + c * KI;
    // stage x -> l = log2(2*clip(x)) : 16 rows x 64
    #pragma unroll
    for (int r = 0; r < (NB * KI) / 256; ++r) {
      int idx = r * 256 + t;
      int k  = idx & (KI - 1);
      int bl = idx >> 6;
      float v = x[(b0 + bl) * 1024 + i0 + k];
      v = fminf(fmaxf(v, 0.0f), 1.0f);
      sL[bl * LROW + k] = LOG2F(2.0f * v);
    }
    // stage params as float4 {A0, E0, A1, E1} : 16 jpairs x 64 k
    #pragma unroll
    for (int r = 0; r < (NJ * KI) / 256; ++r) {
      int idx = r * 256 + t;
      int jl = idx & (NJ - 1);
      int il = idx >> 4;
      int gi = i0 + il;
      float wp = w_pos[gi * 512 + j0 + jl];
      float wn = w_neg[gi * 512 + j0 + jl];
      float2 np = np2[gi * 512 + j0 + jl];   // (n[i,2j], n[i,2j+1])
      sP[jl * KROW4 + il] = make_float4(
          fmaf(0.5f, fabsf(wp), c0), LOG2F(np.x) + 1.0f,
          fmaf(0.5f, fabsf(wn), c0), LOG2F(np.y) + 1.0f);
    }
    __syncthreads();
    const float4* pP = &sP[jj * KROW4];
    const float*  pL = &sL[bb * LROW];
    #pragma unroll 8
    for (int k = 0; k < KI; ++k) {
      float4 p = pP[k];
      float l  = pL[k];
      accP = fmaf(p.x, EXP2F(p.y * l), accP);
      accN = fmaf(p.z, EXP2F(p.w * l), accN);
    }
    __syncthreads();
  }

  if (zt == 7) {
    // bias row i = 1024: inp = 1 -> vr = 2 -> 2^e
    int jg = j0 + jj;
    float2 np = np2[1024 * 512 + jg];
    float a0 = fmaf(0.5f, fabsf(b_pos[jg]), c0);
    float a1 = fmaf(0.5f, fabsf(b_neg[jg]), c0);
    accP = fmaf(a0, EXP2F(LOG2F(np.x) + 1.0f), accP);
    accN = fmaf(a1, EXP2F(LOG2F(np.y) + 1.0f), accN);
  }

  atomicAdd(&y[(b0 + bb) * 512 + (j0 + jj)], accP - accN);
}

extern "C" void kernel_launch(void* const* d_in, const int* in_sizes, int n_in,
                              void* d_out, int out_size, void* d_ws, size_t ws_size,
                              hipStream_t stream) {
  const float* x       = (const float*)d_in[0];
  const float* w_pos   = (const float*)d_in[1];
  const float* w_neg   = (const float*)d_in[2];
  const float* b_pos   = (const float*)d_in[3];
  const float* b_neg   = (const float*)d_in[4];
  const float* n_param = (const float*)d_in[5];
  float* y   = (float*)d_out;

  setup_kernel<<<dim3(256), dim3(256), 0, stream>>>(
      w_pos, w_neg, b_pos, b_neg, y, (int*)d_ws);

  memristor_kernel<<<dim3(32, 8, 8), dim3(256), 0, stream>>>(
      x, w_pos, w_neg, b_pos, b_neg, n_param, (const float*)d_ws, y);
}

// Round 11
// 87.578 us; speedup vs baseline: 1.0725x; 1.0444x over previous
//
#include <hip/hip_runtime.h>
#include <hip/hip_bf16.h>

// memristor_dense: y[b,j] = sum_i A[i,2j]*2^(e[i,2j]*l[b,i]) - A[i,2j+1]*2^(e[i,2j+1]*l[b,i])
//   A[i,j] = 0.5*|w[i,j]| + max_w/18, e = log2(n_param)+1, l = log2(2*clip(x))
// shapes: x(128,1024), w_pos/w_neg(1024,512), b_pos/b_neg(512), n_param(1025,1024)
//
// R10 -> R11: same design as R10 (4 rows/thread, k-major tiles, 2x ds_read_b128
// per k-iter serving 256 pair-evals; grid (32,2,32), 16.9KB LDS -> 8 blocks/CU)
// with two crash-defensive fixes: sL declared natively as __shared__ float4
// (guaranteed 16B alignment for ds_read_b128; R10 cast a 4B-aligned float
// array) and __launch_bounds__(256,8) dropped (forced VGPR<=64 budget may have
// produced a bad binary). Setup unchanged: atomicMax into poisoned ws, y
// zeroed in setup, 2 dispatches, no memset.

#define LOG2F(v)  __builtin_amdgcn_logf(v)    // v_log_f32: log2(x)
#define EXP2F(v)  __builtin_amdgcn_exp2f(v)   // v_exp_f32: 2^x

#define NJ 16        // jpairs per block
#define NB 64        // batch rows per block (4 per thread)
#define KI 32        // i-rows per block (one chunk, z-split 32)
#define SLS4 17      // sL k-row stride in float4 (16 rows-of-4 + pad)

__global__ __launch_bounds__(256) void setup_kernel(
    const float* __restrict__ w_pos, const float* __restrict__ w_neg,
    const float* __restrict__ b_pos, const float* __restrict__ b_neg,
    float* __restrict__ y, int* __restrict__ ws) {
  const int t = threadIdx.x, blk = blockIdx.x;
  // zero d_out: 16384 float4 over 256 blocks = 64 per block
  float4* y4 = (float4*)y;
  if (t < 64) y4[blk * 64 + t] = make_float4(0.f, 0.f, 0.f, 0.f);
  // |w| max partial: each array 131072 float4 -> 512 per block -> 2 per thread
  const float4* wp4 = (const float4*)w_pos;
  const float4* wn4 = (const float4*)w_neg;
  float m = 0.0f;
  #pragma unroll
  for (int r = 0; r < 2; ++r) {
    int i = blk * 512 + r * 256 + t;
    float4 a = wp4[i], b = wn4[i];
    m = fmaxf(m, fmaxf(fmaxf(fabsf(a.x), fabsf(a.y)), fmaxf(fabsf(a.z), fabsf(a.w))));
    m = fmaxf(m, fmaxf(fmaxf(fabsf(b.x), fabsf(b.y)), fmaxf(fabsf(b.z), fabsf(b.w))));
  }
  if (blk == 0) {
    m = fmaxf(m, fmaxf(fabsf(b_pos[t]), fabsf(b_pos[t + 256])));
    m = fmaxf(m, fmaxf(fabsf(b_neg[t]), fabsf(b_neg[t + 256])));
  }
  #pragma unroll
  for (int off = 32; off > 0; off >>= 1)
    m = fmaxf(m, __shfl_down(m, off, 64));
  __shared__ float sm[4];
  int lane = t & 63, wv = t >> 6;
  if (lane == 0) sm[wv] = m;
  __syncthreads();
  if (t == 0) {
    m = fmaxf(fmaxf(sm[0], sm[1]), fmaxf(sm[2], sm[3]));
    // positive-float bits compare correctly as int; poisoned 0xAAAAAAAA is
    // negative as int, so ws needs no initialization.
    atomicMax(ws, __float_as_int(m));
  }
}

__global__ __launch_bounds__(256) void memristor_kernel(
    const float* __restrict__ x, const float* __restrict__ w_pos,
    const float* __restrict__ w_neg, const float* __restrict__ b_pos,
    const float* __restrict__ b_neg, const float* __restrict__ n_param,
    const float* __restrict__ ws, float* __restrict__ y) {
  __shared__ float4 sP[KI * NJ];     // [k][jj] = {A0,E0,A1,E1}, k-major
  __shared__ float4 sL4[KI * SLS4];  // [k][row/4], k-major; 16B-aligned by type

  const float mw = __int_as_float(((const int*)ws)[0]);
  const float c0 = mw * (0.05f / 0.9f);   // G_MIN*V_REF/(K_V*k_G) = max_w/18

  const int j0 = blockIdx.x * NJ;   // 32 j-tiles
  const int b0 = blockIdx.y * NB;   // 2 b-tiles
  const int zt = blockIdx.z;        // 32-way i-split: rows [zt*32, zt*32+32)
  const int i0 = zt * KI;
  const int t  = threadIdx.x;
  const int jj = t & 15;
  const int bq = t >> 4;            // [0,16): rows 4bq..4bq+3

  const float2* np2 = (const float2*)n_param;

  // stage params k-major: 32 i x 16 j = 512 entries, 2 per thread
  #pragma unroll
  for (int r = 0; r < 2; ++r) {
    int il = r * 16 + (t >> 4);
    int jl = t & 15;
    int gi = i0 + il;
    float wp = w_pos[gi * 512 + j0 + jl];
    float wn = w_neg[gi * 512 + j0 + jl];
    float2 np = np2[gi * 512 + j0 + jl];
    sP[il * NJ + jl] = make_float4(
        fmaf(0.5f, fabsf(wp), c0), LOG2F(np.x) + 1.0f,
        fmaf(0.5f, fabsf(wn), c0), LOG2F(np.y) + 1.0f);
  }
  // stage x transposed: 64 rows x 32 k; coalesced float4 reads, scalar writes
  {
    float* sL = (float*)sL4;
    const float4* x4 = (const float4*)x;
    #pragma unroll
    for (int r = 0; r < 2; ++r) {
      int row = r * 32 + (t >> 3);
      int k4  = t & 7;
      float4 v = x4[(b0 + row) * 256 + zt * 8 + k4];
      v.x = fminf(fmaxf(v.x, 0.0f), 1.0f);
      v.y = fminf(fmaxf(v.y, 0.0f), 1.0f);
      v.z = fminf(fmaxf(v.z, 0.0f), 1.0f);
      v.w = fminf(fmaxf(v.w, 0.0f), 1.0f);
      sL[(4 * k4 + 0) * (4 * SLS4) + row] = LOG2F(2.0f * v.x);
      sL[(4 * k4 + 1) * (4 * SLS4) + row] = LOG2F(2.0f * v.y);
      sL[(4 * k4 + 2) * (4 * SLS4) + row] = LOG2F(2.0f * v.z);
      sL[(4 * k4 + 3) * (4 * SLS4) + row] = LOG2F(2.0f * v.w);
    }
  }
  __syncthreads();

  float a0 = 0.0f, a1 = 0.0f, a2 = 0.0f, a3 = 0.0f;
  #pragma unroll 4
  for (int k = 0; k < KI; ++k) {
    float4 p = sP[k * NJ + jj];            // one b128, 16 addrs, 2-way banks
    float4 l = sL4[k * SLS4 + bq];         // one b128, 4 addrs, conflict-free
    a0 = fmaf(p.x, EXP2F(p.y * l.x), fmaf(-p.z, EXP2F(p.w * l.x), a0));
    a1 = fmaf(p.x, EXP2F(p.y * l.y), fmaf(-p.z, EXP2F(p.w * l.y), a1));
    a2 = fmaf(p.x, EXP2F(p.y * l.z), fmaf(-p.z, EXP2F(p.w * l.z), a2));
    a3 = fmaf(p.x, EXP2F(p.y * l.w), fmaf(-p.z, EXP2F(p.w * l.w), a3));
  }

  if (zt == 31) {
    // bias row i = 1024: inp = 1 -> vr = 2 -> 2^e; same for every b row
    int jg = j0 + jj;
    float2 np = np2[1024 * 512 + jg];
    float p0 = fmaf(0.5f, fabsf(b_pos[jg]), c0);
    float p1 = fmaf(0.5f, fabsf(b_neg[jg]), c0);
    float bias = p0 * EXP2F(LOG2F(np.x) + 1.0f) - p1 * EXP2F(LOG2F(np.y) + 1.0f);
    a0 += bias; a1 += bias; a2 += bias; a3 += bias;
  }

  const int row0 = b0 + 4 * bq;
  atomicAdd(&y[(row0 + 0) * 512 + j0 + jj], a0);
  atomicAdd(&y[(row0 + 1) * 512 + j0 + jj], a1);
  atomicAdd(&y[(row0 + 2) * 512 + j0 + jj], a2);
  atomicAdd(&y[(row0 + 3) * 512 + j0 + jj], a3);
}

extern "C" void kernel_launch(void* const* d_in, const int* in_sizes, int n_in,
                              void* d_out, int out_size, void* d_ws, size_t ws_size,
                              hipStream_t stream) {
  const float* x       = (const float*)d_in[0];
  const float* w_pos   = (const float*)d_in[1];
  const float* w_neg   = (const float*)d_in[2];
  const float* b_pos   = (const float*)d_in[3];
  const float* b_neg   = (const float*)d_in[4];
  const float* n_param = (const float*)d_in[5];
  float* y   = (float*)d_out;

  setup_kernel<<<dim3(256), dim3(256), 0, stream>>>(
      w_pos, w_neg, b_pos, b_neg, y, (int*)d_ws);

  memristor_kernel<<<dim3(32, 2, 32), dim3(256), 0, stream>>>(
      x, w_pos, w_neg, b_pos, b_neg, n_param, (const float*)d_ws, y);
}